// Round 6
// baseline (574.984 us; speedup 1.0000x reference)
//
#include <hip/hip_runtime.h>
#include <cstdint>
#include <cstddef>

typedef float    f32x16 __attribute__((ext_vector_type(16)));
typedef __bf16   bf16x8 __attribute__((ext_vector_type(8)));
typedef unsigned u32x2  __attribute__((ext_vector_type(2)));
typedef unsigned u32x4  __attribute__((ext_vector_type(4)));

static_assert(sizeof(bf16x8) == 16, "bf16x8 must be 16B");

#define DEV __device__ __forceinline__

// round-to-nearest-even float -> bf16 bits
DEV unsigned f2bf_bits(float f) {
    unsigned u = __builtin_bit_cast(unsigned, f);
    return ((u + 0x7fffu + ((u >> 16) & 1u)) >> 16) & 0xffffu;
}
DEV float bf2f(unsigned bits) {
    return __builtin_bit_cast(float, bits << 16);
}
DEV unsigned pack2(float a, float b) {
    return f2bf_bits(a) | (f2bf_bits(b) << 16);
}

typedef __attribute__((address_space(1))) const void gas_t;
typedef __attribute__((address_space(3))) void       las_t;
DEV void gload_lds16(const void* g, void* l) {
    __builtin_amdgcn_global_load_lds((gas_t*)g, (las_t*)l, 16, 0, 0);
}

constexpr int D     = 64;
constexpr int SLEN  = 4096;
constexpr int KBLK  = 128;   // semantic block size (must match reference BLOCK_SIZE)
constexpr int NBLK  = SLEN / KBLK;
constexpr int QTILE = 128;   // 4 waves * 32 q-rows
constexpr int VSTR  = 136;   // (fallback kernel only)
constexpr int NBH   = 32;    // B*H
constexpr size_t IMG = 8192;                 // elems per (bh,kb) image (16 KB)
constexpr size_t TEN = (size_t)NBH * NBLK * IMG;  // 8,388,608 elems per tensor

// ============================================================================
// Pre-pass: convert K -> bf16 hi/lo frag-linear images, V -> swizzled V^T
// images, in d_ws. One block per (kb, bh). Memory-bound one-shot (~117 MB).
// ============================================================================
__global__ __launch_bounds__(256, 2)
void prep(const float* __restrict__ Kg, const float* __restrict__ Vg,
          unsigned short* __restrict__ khi_g, unsigned short* __restrict__ klo_g,
          unsigned short* __restrict__ vt_g)
{
    const int tid = threadIdx.x;
    const int kb  = blockIdx.x;
    const int bh  = blockIdx.y;
    const long base = (long)bh * SLEN * D;
    const int  kv0  = kb * KBLK;
    const size_t img = (size_t)(bh * NBLK + kb) * IMG;

    // ---- K: hi/lo split, frag-linear chunks (identical layout to LDS image)
#pragma unroll
    for (int i = 0; i < 4; ++i) {
        int chunk = i * 256 + tid;            // [0,1024)
        int ki  = chunk >> 8;
        int c   = (chunk >> 6) & 3;
        int cl  = chunk & 63;
        int row = ki * 32 + (cl & 31);
        int d0  = c * 16 + (cl >> 5) * 8;
        const float* kp = Kg + base + (long)(kv0 + row) * D + d0;
        float4 x0 = *(const float4*)kp;
        float4 x1 = *(const float4*)(kp + 4);
        float xs[8] = {x0.x, x0.y, x0.z, x0.w, x1.x, x1.y, x1.z, x1.w};
        unsigned hw[4], lw[4];
#pragma unroll
        for (int j = 0; j < 4; ++j) {
            float a = xs[2 * j], b = xs[2 * j + 1];
            unsigned ha = f2bf_bits(a), hb = f2bf_bits(b);
            lw[j] = f2bf_bits(a - bf2f(ha)) | (f2bf_bits(b - bf2f(hb)) << 16);
            hw[j] = ha | (hb << 16);
        }
        u32x4 H = {hw[0], hw[1], hw[2], hw[3]};
        u32x4 L = {lw[0], lw[1], lw[2], lw[3]};
        *(u32x4*)&khi_g[img + (size_t)chunk * 8] = H;
        *(u32x4*)&klo_g[img + (size_t)chunk * 8] = L;
    }

    // ---- V: quad-transpose to V^T, bf16, XOR-swizzled (kv ^ ((d&7)<<3))
    const int e  = tid & 3;
    const int e0 = e & 1, e1 = e >> 1;
    const int DQi = (tid >> 2) & 15;
    const int w   = tid >> 6;
#pragma unroll
    for (int i = 0; i < 8; ++i) {
        int KQ = (i * 4 + w) * 4;             // kv-quad base
        int DQ = DQi * 4;                     // d-quad base
        float4 x = *(const float4*)(Vg + base + (long)(kv0 + KQ + e) * D + DQ);
        float f0 = x.x, f1 = x.y, f2 = x.z, f3 = x.w;
        float sA0 = e0 ? f0 : f1, sA1 = e0 ? f2 : f3;
        float rA0 = __shfl_xor(sA0, 1, 64), rA1 = __shfl_xor(sA1, 1, 64);
        float A0 = e0 ? rA0 : f0, A1 = e0 ? f1 : rA0;
        float A2 = e0 ? rA1 : f2, A3 = e0 ? f3 : rA1;
        float sB0 = e1 ? A0 : A2, sB1 = e1 ? A1 : A3;
        float rB0 = __shfl_xor(sB0, 2, 64), rB1 = __shfl_xor(sB1, 2, 64);
        float B0 = e1 ? rB0 : A0, B1 = e1 ? rB1 : A1;
        float B2 = e1 ? A2 : rB0, B3 = e1 ? A3 : rB1;
        int d = DQ + e;                       // B_i = V[KQ+i][d] = V^T[d][KQ+i]
        u32x2 p;
        p.x = pack2(B0, B1);
        p.y = pack2(B2, B3);
        int off = d * 128 + (KQ ^ ((d & 7) << 3));   // swizzled elem offset
        *(u32x2*)&vt_g[img + off] = p;
    }
}

// ============================================================================
// Main kernel (pre-pass path): staging = pure global_load_lds, zero VALU.
// ============================================================================
__global__ __launch_bounds__(256, 3)
void fa_fwd2(const float* __restrict__ Qg,
             const unsigned short* __restrict__ khi_g,
             const unsigned short* __restrict__ klo_g,
             const unsigned short* __restrict__ vt_g,
             float* __restrict__ Og)
{
    __shared__ __align__(16) unsigned short khi_l[IMG];
    __shared__ __align__(16) unsigned short klo_l[IMG];
    __shared__ __align__(16) unsigned short vt_l[IMG];

    const int tid = threadIdx.x;
    const int l   = tid & 63;
    const int w   = tid >> 6;
    const int h   = l >> 5;
    const int ln  = l & 31;

    const int  bh   = blockIdx.y;
    const long base = (long)bh * SLEN * D;
    const float* Qb = Qg + base;
    float*       Ob = Og + base;

    // ---- Q fragments (B-operand of S^T = K·Q^T), scale 1/8 folded, hi/lo split
    const int qrow = blockIdx.x * QTILE + w * 32 + ln;
    bf16x8 qhi[4], qlo[4];
#pragma unroll
    for (int c = 0; c < 4; ++c) {
        const float* qp = Qb + (long)qrow * D + c * 16 + h * 8;
        float4 x0 = *(const float4*)qp;
        float4 x1 = *(const float4*)(qp + 4);
        float xs[8] = {x0.x, x0.y, x0.z, x0.w, x1.x, x1.y, x1.z, x1.w};
        unsigned hw[4], lw[4];
#pragma unroll
        for (int j = 0; j < 4; ++j) {
            float a = xs[2 * j] * 0.125f, b = xs[2 * j + 1] * 0.125f;
            unsigned ha = f2bf_bits(a), hb = f2bf_bits(b);
            lw[j] = f2bf_bits(a - bf2f(ha)) | (f2bf_bits(b - bf2f(hb)) << 16);
            hw[j] = ha | (hb << 16);
        }
        u32x4 H = {hw[0], hw[1], hw[2], hw[3]};
        u32x4 L = {lw[0], lw[1], lw[2], lw[3]};
        qhi[c] = __builtin_bit_cast(bf16x8, H);
        qlo[c] = __builtin_bit_cast(bf16x8, L);
    }

    f32x16 oa0 = {};   // O^T tile (d = 0..31 rows, q = lane&31 col)
    f32x16 oa1 = {};   // O^T tile (d = 32..63)
    f32x16 st[4];

    float mrun = -INFINITY;
    float norm = 0.0f;

#pragma unroll 1
    for (int kb = 0; kb < NBLK; ++kb) {
        const size_t img = (size_t)(bh * NBLK + kb) * IMG;
        const unsigned short* khs = khi_g + img;
        const unsigned short* kls = klo_g + img;
        const unsigned short* vts = vt_g  + img;

        // ---- stage K hi/lo + V^T via direct global->LDS DMA (no VALU) ----
#pragma unroll
        for (int i = 0; i < 4; ++i) {
            int o = (i * 256 + w * 64) * 8;   // wave-uniform LDS elem offset
            int g = o + l * 8;                // per-lane global elem offset
            gload_lds16(khs + g, &khi_l[o]);
            gload_lds16(kls + g, &klo_l[o]);
            gload_lds16(vts + g, &vt_l[o]);
        }

        __syncthreads();   // compiler emits vmcnt(0) drain before s_barrier

        // ---- S^T = K · Q^T, 3-term bf16 split (≈ fp32 scores) ----
#pragma unroll
        for (int ki = 0; ki < 4; ++ki) {
            f32x16 acc = {};
#pragma unroll
            for (int c = 0; c < 4; ++c) {
                int ch = (ki * 4 + c) * 64 + l;
                bf16x8 ah = *(const bf16x8*)&khi_l[ch * 8];
                bf16x8 al = *(const bf16x8*)&klo_l[ch * 8];
                acc = __builtin_amdgcn_mfma_f32_32x32x16_bf16(ah, qhi[c], acc, 0, 0, 0);
                acc = __builtin_amdgcn_mfma_f32_32x32x16_bf16(ah, qlo[c], acc, 0, 0, 0);
                acc = __builtin_amdgcn_mfma_f32_32x32x16_bf16(al, qhi[c], acc, 0, 0, 0);
            }
            st[ki] = acc;
        }

        // ---- softmax (reference's exact recurrence: exp(s - block_max)) ----
        float bm = -INFINITY;
#pragma unroll
        for (int ki = 0; ki < 4; ++ki)
#pragma unroll
            for (int r = 0; r < 16; ++r) bm = fmaxf(bm, st[ki][r]);
        bm = fmaxf(bm, __shfl_xor(bm, 32, 64));

        float newm = fmaxf(mrun, bm);
        float sc   = __expf(mrun - newm);     // first block: exp(-inf) = 0
        mrun = newm;

        float psum = 0.0f;
#pragma unroll
        for (int ki = 0; ki < 4; ++ki) {
#pragma unroll
            for (int r = 0; r < 16; ++r) {
                float p = __expf(st[ki][r] - bm);
                st[ki][r] = p;
                psum += p;
            }
        }
        psum += __shfl_xor(psum, 32, 64);
        norm = norm * sc + psum;

#pragma unroll
        for (int r = 0; r < 16; ++r) { oa0[r] *= sc; oa1[r] *= sc; }

        // ---- build P^T fragments (half-swap across lane 32 boundary) ----
        bf16x8 pf[8];
#pragma unroll
        for (int c = 0; c < 8; ++c) {
            int ki = c >> 1, half = c & 1;
            int rb = half * 8;
            unsigned A0 = pack2(st[ki][rb + 0], st[ki][rb + 1]);
            unsigned A1 = pack2(st[ki][rb + 2], st[ki][rb + 3]);
            unsigned B0 = pack2(st[ki][rb + 4], st[ki][rb + 5]);
            unsigned B1 = pack2(st[ki][rb + 6], st[ki][rb + 7]);
            unsigned s0 = h ? A0 : B0;
            unsigned s1 = h ? A1 : B1;
            unsigned r0 = (unsigned)__shfl_xor((int)s0, 32, 64);
            unsigned r1 = (unsigned)__shfl_xor((int)s1, 32, 64);
            u32x4 f;
            f.x = h ? r0 : A0;
            f.y = h ? r1 : A1;
            f.z = h ? B0 : r0;
            f.w = h ? B1 : r1;
            pf[c] = __builtin_bit_cast(bf16x8, f);
        }

        // ---- O^T += V^T · P^T  (swizzled ds_read_b128, conflict-free) ----
#pragma unroll
        for (int c = 0; c < 8; ++c) {
            const int kvo = c * 16 + h * 8;
            const int sa  = ln * 128 + (kvo ^ ((ln & 7) << 3));
            bf16x8 va = *(const bf16x8*)&vt_l[sa];
            bf16x8 vb = *(const bf16x8*)&vt_l[sa + 4096];
            oa0 = __builtin_amdgcn_mfma_f32_32x32x16_bf16(va, pf[c], oa0, 0, 0, 0);
            oa1 = __builtin_amdgcn_mfma_f32_32x32x16_bf16(vb, pf[c], oa1, 0, 0, 0);
        }

        __syncthreads();
    }

    // ---- epilogue ----
    float inv = 1.0f / (norm + 1e-6f);
    long  orow = (long)qrow * D;
#pragma unroll
    for (int rg = 0; rg < 4; ++rg) {
        int d0 = 8 * rg + 4 * h;
        float4 w0, w1;
        w0.x = oa0[4 * rg + 0] * inv;
        w0.y = oa0[4 * rg + 1] * inv;
        w0.z = oa0[4 * rg + 2] * inv;
        w0.w = oa0[4 * rg + 3] * inv;
        w1.x = oa1[4 * rg + 0] * inv;
        w1.y = oa1[4 * rg + 1] * inv;
        w1.z = oa1[4 * rg + 2] * inv;
        w1.w = oa1[4 * rg + 3] * inv;
        *(float4*)(Ob + orow + d0)      = w0;
        *(float4*)(Ob + orow + 32 + d0) = w1;
    }
}

// ============================================================================
// Fallback kernel (round-4, passing): in-kernel staging, used if ws too small.
// ============================================================================
__global__ __launch_bounds__(256, 2)
void fa_fwd(const float* __restrict__ Qg, const float* __restrict__ Kg,
            const float* __restrict__ Vg, float* __restrict__ Og)
{
    __shared__ __align__(16) unsigned short khi[KBLK * D];
    __shared__ __align__(16) unsigned short klo[KBLK * D];
    __shared__ __align__(16) unsigned short vt[D * VSTR];

    const int tid = threadIdx.x;
    const int l   = tid & 63;
    const int w   = tid >> 6;
    const int h   = l >> 5;
    const int ln  = l & 31;

    const int  bh   = blockIdx.y;
    const long base = (long)bh * SLEN * D;
    const float* Qb = Qg + base;
    const float* Kb = Kg + base;
    const float* Vb = Vg + base;
    float*       Ob = Og + base;

    const int qrow = blockIdx.x * QTILE + w * 32 + ln;
    bf16x8 qhi[4], qlo[4];
#pragma unroll
    for (int c = 0; c < 4; ++c) {
        const float* qp = Qb + (long)qrow * D + c * 16 + h * 8;
        float4 x0 = *(const float4*)qp;
        float4 x1 = *(const float4*)(qp + 4);
        float xs[8] = {x0.x, x0.y, x0.z, x0.w, x1.x, x1.y, x1.z, x1.w};
        unsigned hw[4], lw[4];
#pragma unroll
        for (int j = 0; j < 4; ++j) {
            float a = xs[2 * j] * 0.125f, b = xs[2 * j + 1] * 0.125f;
            unsigned ha = f2bf_bits(a), hb = f2bf_bits(b);
            lw[j] = f2bf_bits(a - bf2f(ha)) | (f2bf_bits(b - bf2f(hb)) << 16);
            hw[j] = ha | (hb << 16);
        }
        u32x4 H = {hw[0], hw[1], hw[2], hw[3]};
        u32x4 L = {lw[0], lw[1], lw[2], lw[3]};
        qhi[c] = __builtin_bit_cast(bf16x8, H);
        qlo[c] = __builtin_bit_cast(bf16x8, L);
    }

    f32x16 oa0 = {};
    f32x16 oa1 = {};
    f32x16 st[4];

    float mrun = -INFINITY;
    float norm = 0.0f;

    const int e  = tid & 3;
    const int e0 = e & 1, e1 = e >> 1;
    const int DQi = (tid >> 2) & 15;

#pragma unroll 1
    for (int kb = 0; kb < NBLK; ++kb) {
        const int kv0 = kb * KBLK;

#pragma unroll
        for (int i = 0; i < 4; ++i) {
            int chunk = i * 256 + tid;
            int ki  = chunk >> 8;
            int c   = (chunk >> 6) & 3;
            int cl  = chunk & 63;
            int row = ki * 32 + (cl & 31);
            int d0  = c * 16 + (cl >> 5) * 8;
            const float* kp = Kb + (long)(kv0 + row) * D + d0;
            float4 x0 = *(const float4*)kp;
            float4 x1 = *(const float4*)(kp + 4);
            float xs[8] = {x0.x, x0.y, x0.z, x0.w, x1.x, x1.y, x1.z, x1.w};
            unsigned hw[4], lw[4];
#pragma unroll
            for (int j = 0; j < 4; ++j) {
                float a = xs[2 * j], b = xs[2 * j + 1];
                unsigned ha = f2bf_bits(a), hb = f2bf_bits(b);
                lw[j] = f2bf_bits(a - bf2f(ha)) | (f2bf_bits(b - bf2f(hb)) << 16);
                hw[j] = ha | (hb << 16);
            }
            u32x4 H = {hw[0], hw[1], hw[2], hw[3]};
            u32x4 L = {lw[0], lw[1], lw[2], lw[3]};
            *(u32x4*)&khi[chunk * 8] = H;
            *(u32x4*)&klo[chunk * 8] = L;
        }

#pragma unroll
        for (int i = 0; i < 8; ++i) {
            int KQ = (i * 4 + w) * 4;
            int DQ = DQi * 4;
            float4 x = *(const float4*)(Vb + (long)(kv0 + KQ + e) * D + DQ);
            float f0 = x.x, f1 = x.y, f2 = x.z, f3 = x.w;
            float sA0 = e0 ? f0 : f1, sA1 = e0 ? f2 : f3;
            float rA0 = __shfl_xor(sA0, 1, 64), rA1 = __shfl_xor(sA1, 1, 64);
            float A0 = e0 ? rA0 : f0, A1 = e0 ? f1 : rA0;
            float A2 = e0 ? rA1 : f2, A3 = e0 ? f3 : rA1;
            float sB0 = e1 ? A0 : A2, sB1 = e1 ? A1 : A3;
            float rB0 = __shfl_xor(sB0, 2, 64), rB1 = __shfl_xor(sB1, 2, 64);
            float B0 = e1 ? rB0 : A0, B1 = e1 ? rB1 : A1;
            float B2 = e1 ? A2 : rB0, B3 = e1 ? A3 : rB1;
            u32x2 p;
            p.x = pack2(B0, B1);
            p.y = pack2(B2, B3);
            *(u32x2*)&vt[(DQ + e) * VSTR + KQ] = p;
        }

        __syncthreads();

#pragma unroll
        for (int ki = 0; ki < 4; ++ki) {
            f32x16 acc = {};
#pragma unroll
            for (int c = 0; c < 4; ++c) {
                int ch = (ki * 4 + c) * 64 + l;
                bf16x8 ah = *(const bf16x8*)&khi[ch * 8];
                bf16x8 al = *(const bf16x8*)&klo[ch * 8];
                acc = __builtin_amdgcn_mfma_f32_32x32x16_bf16(ah, qhi[c], acc, 0, 0, 0);
                acc = __builtin_amdgcn_mfma_f32_32x32x16_bf16(ah, qlo[c], acc, 0, 0, 0);
                acc = __builtin_amdgcn_mfma_f32_32x32x16_bf16(al, qhi[c], acc, 0, 0, 0);
            }
            st[ki] = acc;
        }

        float bm = -INFINITY;
#pragma unroll
        for (int ki = 0; ki < 4; ++ki)
#pragma unroll
            for (int r = 0; r < 16; ++r) bm = fmaxf(bm, st[ki][r]);
        bm = fmaxf(bm, __shfl_xor(bm, 32, 64));

        float newm = fmaxf(mrun, bm);
        float sc   = __expf(mrun - newm);
        mrun = newm;

        float psum = 0.0f;
#pragma unroll
        for (int ki = 0; ki < 4; ++ki) {
#pragma unroll
            for (int r = 0; r < 16; ++r) {
                float p = __expf(st[ki][r] - bm);
                st[ki][r] = p;
                psum += p;
            }
        }
        psum += __shfl_xor(psum, 32, 64);
        norm = norm * sc + psum;

#pragma unroll
        for (int r = 0; r < 16; ++r) { oa0[r] *= sc; oa1[r] *= sc; }

        bf16x8 pf[8];
#pragma unroll
        for (int c = 0; c < 8; ++c) {
            int ki = c >> 1, half = c & 1;
            int rb = half * 8;
            unsigned A0 = pack2(st[ki][rb + 0], st[ki][rb + 1]);
            unsigned A1 = pack2(st[ki][rb + 2], st[ki][rb + 3]);
            unsigned B0 = pack2(st[ki][rb + 4], st[ki][rb + 5]);
            unsigned B1 = pack2(st[ki][rb + 6], st[ki][rb + 7]);
            unsigned s0 = h ? A0 : B0;
            unsigned s1 = h ? A1 : B1;
            unsigned r0 = (unsigned)__shfl_xor((int)s0, 32, 64);
            unsigned r1 = (unsigned)__shfl_xor((int)s1, 32, 64);
            u32x4 f;
            f.x = h ? r0 : A0;
            f.y = h ? r1 : A1;
            f.z = h ? B0 : r0;
            f.w = h ? B1 : r1;
            pf[c] = __builtin_bit_cast(bf16x8, f);
        }

#pragma unroll
        for (int c = 0; c < 8; ++c) {
            const int kvo = c * 16 + h * 8;
            bf16x8 va = *(const bf16x8*)&vt[(ln)      * VSTR + kvo];
            bf16x8 vb = *(const bf16x8*)&vt[(32 + ln) * VSTR + kvo];
            oa0 = __builtin_amdgcn_mfma_f32_32x32x16_bf16(va, pf[c], oa0, 0, 0, 0);
            oa1 = __builtin_amdgcn_mfma_f32_32x32x16_bf16(vb, pf[c], oa1, 0, 0, 0);
        }

        __syncthreads();
    }

    float inv = 1.0f / (norm + 1e-6f);
    long  orow = (long)qrow * D;
#pragma unroll
    for (int rg = 0; rg < 4; ++rg) {
        int d0 = 8 * rg + 4 * h;
        float4 w0, w1;
        w0.x = oa0[4 * rg + 0] * inv;
        w0.y = oa0[4 * rg + 1] * inv;
        w0.z = oa0[4 * rg + 2] * inv;
        w0.w = oa0[4 * rg + 3] * inv;
        w1.x = oa1[4 * rg + 0] * inv;
        w1.y = oa1[4 * rg + 1] * inv;
        w1.z = oa1[4 * rg + 2] * inv;
        w1.w = oa1[4 * rg + 3] * inv;
        *(float4*)(Ob + orow + d0)      = w0;
        *(float4*)(Ob + orow + 32 + d0) = w1;
    }
}

extern "C" void kernel_launch(void* const* d_in, const int* in_sizes, int n_in,
                              void* d_out, int out_size, void* d_ws, size_t ws_size,
                              hipStream_t stream)
{
    (void)in_sizes; (void)n_in; (void)out_size;
    const float* q = (const float*)d_in[0];
    const float* k = (const float*)d_in[1];
    const float* v = (const float*)d_in[2];
    float*       o = (float*)d_out;

    const size_t need = 3 * TEN * sizeof(unsigned short);  // 50,331,648 B

    if (ws_size >= need) {
        unsigned short* khi_g = (unsigned short*)d_ws;
        unsigned short* klo_g = khi_g + TEN;
        unsigned short* vt_g  = klo_g + TEN;

        dim3 pgrid(NBLK, NBH);
        hipLaunchKernelGGL(prep, pgrid, dim3(256), 0, stream, k, v, khi_g, klo_g, vt_g);

        dim3 grid(SLEN / QTILE, NBH);
        hipLaunchKernelGGL(fa_fwd2, grid, dim3(256), 0, stream, q, khi_g, klo_g, vt_g, o);
    } else {
        dim3 grid(SLEN / QTILE, NBH);
        hipLaunchKernelGGL(fa_fwd, grid, dim3(256), 0, stream, q, k, v, o);
    }
}

// Round 7
// 340.348 us; speedup vs baseline: 1.6894x; 1.6894x over previous
//
#include <hip/hip_runtime.h>
#include <cstdint>
#include <cstddef>

typedef float     f32x16 __attribute__((ext_vector_type(16)));
typedef _Float16  f16x8  __attribute__((ext_vector_type(8)));
typedef __bf16    bf16x8 __attribute__((ext_vector_type(8)));
typedef unsigned  u32x2  __attribute__((ext_vector_type(2)));
typedef unsigned  u32x4  __attribute__((ext_vector_type(4)));

static_assert(sizeof(f16x8) == 16, "f16x8 must be 16B");

#define DEV __device__ __forceinline__

// ---- f16 helpers (RNE via HW cvt) ----
DEV unsigned short f2h_bits(float f) {
    _Float16 h = (_Float16)f;
    return __builtin_bit_cast(unsigned short, h);
}
DEV unsigned pack2h(float a, float b) {
    return (unsigned)f2h_bits(a) | ((unsigned)f2h_bits(b) << 16);
}

// ---- bf16 helpers (fallback kernel only) ----
DEV unsigned f2bf_bits(float f) {
    unsigned u = __builtin_bit_cast(unsigned, f);
    return ((u + 0x7fffu + ((u >> 16) & 1u)) >> 16) & 0xffffu;
}
DEV float bf2f(unsigned bits) {
    return __builtin_bit_cast(float, bits << 16);
}
DEV unsigned pack2(float a, float b) {
    return f2bf_bits(a) | (f2bf_bits(b) << 16);
}

typedef __attribute__((address_space(1))) const void gas_t;
typedef __attribute__((address_space(3))) void       las_t;
DEV void gload_lds16(const void* g, void* l) {
    __builtin_amdgcn_global_load_lds((gas_t*)g, (las_t*)l, 16, 0, 0);
}

constexpr int D     = 64;
constexpr int SLEN  = 4096;
constexpr int KBLK  = 128;   // semantic block size (must match reference BLOCK_SIZE)
constexpr int NBLK  = SLEN / KBLK;
constexpr int QTILE = 128;   // 4 waves * 32 q-rows
constexpr int VSTR  = 136;   // (fallback kernel only)
constexpr int NBH   = 32;    // B*H
constexpr size_t IMG = 8192;                 // elems per (bh,kb) image (16 KB)
constexpr size_t TEN = (size_t)NBH * NBLK * IMG;  // 8,388,608 elems per tensor

// ============================================================================
// Pre-pass (f16): K -> f16 frag-linear images, V -> f16 swizzled V^T images.
// V^T staged through LDS so global writes are fully coalesced 16B chunks.
// ============================================================================
__global__ __launch_bounds__(256, 2)
void prep16(const float* __restrict__ Kg, const float* __restrict__ Vg,
            unsigned short* __restrict__ kf_g, unsigned short* __restrict__ vt_g)
{
    __shared__ __align__(16) unsigned short vstage[IMG];

    const int tid = threadIdx.x;
    const int kb  = blockIdx.x;
    const int bh  = blockIdx.y;
    const long base = (long)bh * SLEN * D;
    const int  kv0  = kb * KBLK;
    const size_t img = (size_t)(bh * NBLK + kb) * IMG;

    // ---- K: f16, frag-linear chunks (identical layout to LDS image) ----
#pragma unroll
    for (int i = 0; i < 4; ++i) {
        int chunk = i * 256 + tid;            // [0,1024)
        int ki  = chunk >> 8;
        int c   = (chunk >> 6) & 3;
        int cl  = chunk & 63;
        int row = ki * 32 + (cl & 31);
        int d0  = c * 16 + (cl >> 5) * 8;
        const float* kp = Kg + base + (long)(kv0 + row) * D + d0;
        float4 x0 = *(const float4*)kp;
        float4 x1 = *(const float4*)(kp + 4);
        u32x4 H;
        H.x = pack2h(x0.x, x0.y);
        H.y = pack2h(x0.z, x0.w);
        H.z = pack2h(x1.x, x1.y);
        H.w = pack2h(x1.z, x1.w);
        *(u32x4*)&kf_g[img + (size_t)chunk * 8] = H;
    }

    // ---- V: quad-transpose to V^T f16, XOR-swizzled, into LDS stage ----
    const int e  = tid & 3;
    const int e0 = e & 1, e1 = e >> 1;
    const int DQi = (tid >> 2) & 15;
    const int w   = tid >> 6;
#pragma unroll
    for (int i = 0; i < 8; ++i) {
        int KQ = (i * 4 + w) * 4;             // kv-quad base
        int DQ = DQi * 4;                     // d-quad base
        float4 x = *(const float4*)(Vg + base + (long)(kv0 + KQ + e) * D + DQ);
        float f0 = x.x, f1 = x.y, f2 = x.z, f3 = x.w;
        float sA0 = e0 ? f0 : f1, sA1 = e0 ? f2 : f3;
        float rA0 = __shfl_xor(sA0, 1, 64), rA1 = __shfl_xor(sA1, 1, 64);
        float A0 = e0 ? rA0 : f0, A1 = e0 ? f1 : rA0;
        float A2 = e0 ? rA1 : f2, A3 = e0 ? f3 : rA1;
        float sB0 = e1 ? A0 : A2, sB1 = e1 ? A1 : A3;
        float rB0 = __shfl_xor(sB0, 2, 64), rB1 = __shfl_xor(sB1, 2, 64);
        float B0 = e1 ? rB0 : A0, B1 = e1 ? rB1 : A1;
        float B2 = e1 ? A2 : rB0, B3 = e1 ? A3 : rB1;
        int d = DQ + e;                       // B_i = V[KQ+i][d] = V^T[d][KQ+i]
        u32x2 p;
        p.x = pack2h(B0, B1);
        p.y = pack2h(B2, B3);
        int off = d * 128 + (KQ ^ ((d & 7) << 3));   // swizzled elem offset
        *(u32x2*)&vstage[off] = p;
    }

    __syncthreads();

    // ---- coalesced copy-out of the swizzled V^T image ----
#pragma unroll
    for (int i = 0; i < 4; ++i) {
        size_t t8 = (size_t)(i * 256 + tid) * 8;
        *(u32x4*)&vt_g[img + t8] = *(const u32x4*)&vstage[t8];
    }
}

// ============================================================================
// Main kernel (f16 path): 32 MFMA/wave/iter, staging via global_load_lds DMA.
// ============================================================================
__global__ __launch_bounds__(256, 3)
void fa_fwd3(const float* __restrict__ Qg,
             const unsigned short* __restrict__ kf_g,
             const unsigned short* __restrict__ vt_g,
             float* __restrict__ Og)
{
    __shared__ __align__(16) unsigned short kf_l[IMG];
    __shared__ __align__(16) unsigned short vt_l[IMG];

    const int tid = threadIdx.x;
    const int l   = tid & 63;
    const int w   = tid >> 6;
    const int h   = l >> 5;
    const int ln  = l & 31;

    const int  bh   = blockIdx.y;
    const long base = (long)bh * SLEN * D;
    const float* Qb = Qg + base;
    float*       Ob = Og + base;

    // ---- Q fragments (B-operand of S^T = K·Q^T), scale 1/8 folded, f16 ----
    const int qrow = blockIdx.x * QTILE + w * 32 + ln;
    f16x8 qf[4];
#pragma unroll
    for (int c = 0; c < 4; ++c) {
        const float* qp = Qb + (long)qrow * D + c * 16 + h * 8;
        float4 x0 = *(const float4*)qp;
        float4 x1 = *(const float4*)(qp + 4);
        u32x4 H;
        H.x = pack2h(x0.x * 0.125f, x0.y * 0.125f);
        H.y = pack2h(x0.z * 0.125f, x0.w * 0.125f);
        H.z = pack2h(x1.x * 0.125f, x1.y * 0.125f);
        H.w = pack2h(x1.z * 0.125f, x1.w * 0.125f);
        qf[c] = __builtin_bit_cast(f16x8, H);
    }

    f32x16 oa0 = {};   // O^T tile (d = 0..31 rows, q = lane&31 col)
    f32x16 oa1 = {};   // O^T tile (d = 32..63)
    f32x16 st[4];

    float mrun = -INFINITY;
    float norm = 0.0f;

#pragma unroll 1
    for (int kb = 0; kb < NBLK; ++kb) {
        const size_t img = (size_t)(bh * NBLK + kb) * IMG;
        const unsigned short* kfs = kf_g + img;
        const unsigned short* vts = vt_g + img;

        // ---- stage K + V^T via direct global->LDS DMA (no VALU) ----
#pragma unroll
        for (int i = 0; i < 4; ++i) {
            int o = (i * 256 + w * 64) * 8;   // wave-uniform LDS elem offset
            int g = o + l * 8;                // per-lane global elem offset
            gload_lds16(kfs + g, &kf_l[o]);
            gload_lds16(vts + g, &vt_l[o]);
        }

        __syncthreads();

        // ---- S^T = K · Q^T, single f16 product (err std ~1e-4) ----
#pragma unroll
        for (int ki = 0; ki < 4; ++ki) {
            f32x16 acc = {};
#pragma unroll
            for (int c = 0; c < 4; ++c) {
                int ch = (ki * 4 + c) * 64 + l;
                f16x8 a = *(const f16x8*)&kf_l[ch * 8];
                acc = __builtin_amdgcn_mfma_f32_32x32x16_f16(a, qf[c], acc, 0, 0, 0);
            }
            st[ki] = acc;
        }

        // ---- softmax (reference's exact recurrence: exp(s - block_max)) ----
        float bm = -INFINITY;
#pragma unroll
        for (int ki = 0; ki < 4; ++ki)
#pragma unroll
            for (int r = 0; r < 16; ++r) bm = fmaxf(bm, st[ki][r]);
        bm = fmaxf(bm, __shfl_xor(bm, 32, 64));

        float newm = fmaxf(mrun, bm);
        float sc   = __expf(mrun - newm);     // first block: exp(-inf) = 0
        mrun = newm;

        float psum = 0.0f;
#pragma unroll
        for (int ki = 0; ki < 4; ++ki) {
#pragma unroll
            for (int r = 0; r < 16; ++r) {
                float p = __expf(st[ki][r] - bm);
                st[ki][r] = p;
                psum += p;
            }
        }
        psum += __shfl_xor(psum, 32, 64);
        norm = norm * sc + psum;

        if (__any(sc != 1.0f)) {              // exact skip: exp(0)==1
#pragma unroll
            for (int r = 0; r < 16; ++r) { oa0[r] *= sc; oa1[r] *= sc; }
        }

        // ---- build P^T fragments f16 (half-swap across lane 32 boundary) ----
        f16x8 pf[8];
#pragma unroll
        for (int c = 0; c < 8; ++c) {
            int ki = c >> 1, half = c & 1;
            int rb = half * 8;
            unsigned A0 = pack2h(st[ki][rb + 0], st[ki][rb + 1]);
            unsigned A1 = pack2h(st[ki][rb + 2], st[ki][rb + 3]);
            unsigned B0 = pack2h(st[ki][rb + 4], st[ki][rb + 5]);
            unsigned B1 = pack2h(st[ki][rb + 6], st[ki][rb + 7]);
            unsigned s0 = h ? A0 : B0;
            unsigned s1 = h ? A1 : B1;
            unsigned r0 = (unsigned)__shfl_xor((int)s0, 32, 64);
            unsigned r1 = (unsigned)__shfl_xor((int)s1, 32, 64);
            u32x4 f;
            f.x = h ? r0 : A0;
            f.y = h ? r1 : A1;
            f.z = h ? B0 : r0;
            f.w = h ? B1 : r1;
            pf[c] = __builtin_bit_cast(f16x8, f);
        }

        // ---- O^T += V^T · P^T  (swizzled ds_read_b128) ----
#pragma unroll
        for (int c = 0; c < 8; ++c) {
            const int kvo = c * 16 + h * 8;
            const int sa  = ln * 128 + (kvo ^ ((ln & 7) << 3));
            f16x8 va = *(const f16x8*)&vt_l[sa];
            f16x8 vb = *(const f16x8*)&vt_l[sa + 4096];
            oa0 = __builtin_amdgcn_mfma_f32_32x32x16_f16(va, pf[c], oa0, 0, 0, 0);
            oa1 = __builtin_amdgcn_mfma_f32_32x32x16_f16(vb, pf[c], oa1, 0, 0, 0);
        }

        __syncthreads();
    }

    // ---- epilogue ----
    float inv = 1.0f / (norm + 1e-6f);
    long  orow = (long)qrow * D;
#pragma unroll
    for (int rg = 0; rg < 4; ++rg) {
        int d0 = 8 * rg + 4 * h;
        float4 w0, w1;
        w0.x = oa0[4 * rg + 0] * inv;
        w0.y = oa0[4 * rg + 1] * inv;
        w0.z = oa0[4 * rg + 2] * inv;
        w0.w = oa0[4 * rg + 3] * inv;
        w1.x = oa1[4 * rg + 0] * inv;
        w1.y = oa1[4 * rg + 1] * inv;
        w1.z = oa1[4 * rg + 2] * inv;
        w1.w = oa1[4 * rg + 3] * inv;
        *(float4*)(Ob + orow + d0)      = w0;
        *(float4*)(Ob + orow + 32 + d0) = w1;
    }
}

// ============================================================================
// Fallback kernel (round-4, verified): in-kernel bf16 staging, if ws too small.
// ============================================================================
__global__ __launch_bounds__(256, 2)
void fa_fwd(const float* __restrict__ Qg, const float* __restrict__ Kg,
            const float* __restrict__ Vg, float* __restrict__ Og)
{
    __shared__ __align__(16) unsigned short khi[KBLK * D];
    __shared__ __align__(16) unsigned short klo[KBLK * D];
    __shared__ __align__(16) unsigned short vt[D * VSTR];

    const int tid = threadIdx.x;
    const int l   = tid & 63;
    const int w   = tid >> 6;
    const int h   = l >> 5;
    const int ln  = l & 31;

    const int  bh   = blockIdx.y;
    const long base = (long)bh * SLEN * D;
    const float* Qb = Qg + base;
    const float* Kb = Kg + base;
    const float* Vb = Vg + base;
    float*       Ob = Og + base;

    const int qrow = blockIdx.x * QTILE + w * 32 + ln;
    bf16x8 qhi[4], qlo[4];
#pragma unroll
    for (int c = 0; c < 4; ++c) {
        const float* qp = Qb + (long)qrow * D + c * 16 + h * 8;
        float4 x0 = *(const float4*)qp;
        float4 x1 = *(const float4*)(qp + 4);
        float xs[8] = {x0.x, x0.y, x0.z, x0.w, x1.x, x1.y, x1.z, x1.w};
        unsigned hw[4], lw[4];
#pragma unroll
        for (int j = 0; j < 4; ++j) {
            float a = xs[2 * j] * 0.125f, b = xs[2 * j + 1] * 0.125f;
            unsigned ha = f2bf_bits(a), hb = f2bf_bits(b);
            lw[j] = f2bf_bits(a - bf2f(ha)) | (f2bf_bits(b - bf2f(hb)) << 16);
            hw[j] = ha | (hb << 16);
        }
        u32x4 H = {hw[0], hw[1], hw[2], hw[3]};
        u32x4 L = {lw[0], lw[1], lw[2], lw[3]};
        qhi[c] = __builtin_bit_cast(bf16x8, H);
        qlo[c] = __builtin_bit_cast(bf16x8, L);
    }

    f32x16 oa0 = {};
    f32x16 oa1 = {};
    f32x16 st[4];

    float mrun = -INFINITY;
    float norm = 0.0f;

    const int e  = tid & 3;
    const int e0 = e & 1, e1 = e >> 1;
    const int DQi = (tid >> 2) & 15;

#pragma unroll 1
    for (int kb = 0; kb < NBLK; ++kb) {
        const int kv0 = kb * KBLK;

#pragma unroll
        for (int i = 0; i < 4; ++i) {
            int chunk = i * 256 + tid;
            int ki  = chunk >> 8;
            int c   = (chunk >> 6) & 3;
            int cl  = chunk & 63;
            int row = ki * 32 + (cl & 31);
            int d0  = c * 16 + (cl >> 5) * 8;
            const float* kp = Kb + (long)(kv0 + row) * D + d0;
            float4 x0 = *(const float4*)kp;
            float4 x1 = *(const float4*)(kp + 4);
            float xs[8] = {x0.x, x0.y, x0.z, x0.w, x1.x, x1.y, x1.z, x1.w};
            unsigned hw[4], lw[4];
#pragma unroll
            for (int j = 0; j < 4; ++j) {
                float a = xs[2 * j], b = xs[2 * j + 1];
                unsigned ha = f2bf_bits(a), hb = f2bf_bits(b);
                lw[j] = f2bf_bits(a - bf2f(ha)) | (f2bf_bits(b - bf2f(hb)) << 16);
                hw[j] = ha | (hb << 16);
            }
            u32x4 H = {hw[0], hw[1], hw[2], hw[3]};
            u32x4 L = {lw[0], lw[1], lw[2], lw[3]};
            *(u32x4*)&khi[chunk * 8] = H;
            *(u32x4*)&klo[chunk * 8] = L;
        }

#pragma unroll
        for (int i = 0; i < 8; ++i) {
            int KQ = (i * 4 + w) * 4;
            int DQ = DQi * 4;
            float4 x = *(const float4*)(Vb + (long)(kv0 + KQ + e) * D + DQ);
            float f0 = x.x, f1 = x.y, f2 = x.z, f3 = x.w;
            float sA0 = e0 ? f0 : f1, sA1 = e0 ? f2 : f3;
            float rA0 = __shfl_xor(sA0, 1, 64), rA1 = __shfl_xor(sA1, 1, 64);
            float A0 = e0 ? rA0 : f0, A1 = e0 ? f1 : rA0;
            float A2 = e0 ? rA1 : f2, A3 = e0 ? f3 : rA1;
            float sB0 = e1 ? A0 : A2, sB1 = e1 ? A1 : A3;
            float rB0 = __shfl_xor(sB0, 2, 64), rB1 = __shfl_xor(sB1, 2, 64);
            float B0 = e1 ? rB0 : A0, B1 = e1 ? rB1 : A1;
            float B2 = e1 ? A2 : rB0, B3 = e1 ? A3 : rB1;
            u32x2 p;
            p.x = pack2(B0, B1);
            p.y = pack2(B2, B3);
            *(u32x2*)&vt[(DQ + e) * VSTR + KQ] = p;
        }

        __syncthreads();

#pragma unroll
        for (int ki = 0; ki < 4; ++ki) {
            f32x16 acc = {};
#pragma unroll
            for (int c = 0; c < 4; ++c) {
                int ch = (ki * 4 + c) * 64 + l;
                bf16x8 ah = *(const bf16x8*)&khi[ch * 8];
                bf16x8 al = *(const bf16x8*)&klo[ch * 8];
                acc = __builtin_amdgcn_mfma_f32_32x32x16_bf16(ah, qhi[c], acc, 0, 0, 0);
                acc = __builtin_amdgcn_mfma_f32_32x32x16_bf16(ah, qlo[c], acc, 0, 0, 0);
                acc = __builtin_amdgcn_mfma_f32_32x32x16_bf16(al, qhi[c], acc, 0, 0, 0);
            }
            st[ki] = acc;
        }

        float bm = -INFINITY;
#pragma unroll
        for (int ki = 0; ki < 4; ++ki)
#pragma unroll
            for (int r = 0; r < 16; ++r) bm = fmaxf(bm, st[ki][r]);
        bm = fmaxf(bm, __shfl_xor(bm, 32, 64));

        float newm = fmaxf(mrun, bm);
        float sc   = __expf(mrun - newm);
        mrun = newm;

        float psum = 0.0f;
#pragma unroll
        for (int ki = 0; ki < 4; ++ki) {
#pragma unroll
            for (int r = 0; r < 16; ++r) {
                float p = __expf(st[ki][r] - bm);
                st[ki][r] = p;
                psum += p;
            }
        }
        psum += __shfl_xor(psum, 32, 64);
        norm = norm * sc + psum;

#pragma unroll
        for (int r = 0; r < 16; ++r) { oa0[r] *= sc; oa1[r] *= sc; }

        bf16x8 pf[8];
#pragma unroll
        for (int c = 0; c < 8; ++c) {
            int ki = c >> 1, half = c & 1;
            int rb = half * 8;
            unsigned A0 = pack2(st[ki][rb + 0], st[ki][rb + 1]);
            unsigned A1 = pack2(st[ki][rb + 2], st[ki][rb + 3]);
            unsigned B0 = pack2(st[ki][rb + 4], st[ki][rb + 5]);
            unsigned B1 = pack2(st[ki][rb + 6], st[ki][rb + 7]);
            unsigned s0 = h ? A0 : B0;
            unsigned s1 = h ? A1 : B1;
            unsigned r0 = (unsigned)__shfl_xor((int)s0, 32, 64);
            unsigned r1 = (unsigned)__shfl_xor((int)s1, 32, 64);
            u32x4 f;
            f.x = h ? r0 : A0;
            f.y = h ? r1 : A1;
            f.z = h ? B0 : r0;
            f.w = h ? B1 : r1;
            pf[c] = __builtin_bit_cast(bf16x8, f);
        }

#pragma unroll
        for (int c = 0; c < 8; ++c) {
            const int kvo = c * 16 + h * 8;
            bf16x8 va = *(const bf16x8*)&vt[(ln)      * VSTR + kvo];
            bf16x8 vb = *(const bf16x8*)&vt[(32 + ln) * VSTR + kvo];
            oa0 = __builtin_amdgcn_mfma_f32_32x32x16_bf16(va, pf[c], oa0, 0, 0, 0);
            oa1 = __builtin_amdgcn_mfma_f32_32x32x16_bf16(vb, pf[c], oa1, 0, 0, 0);
        }

        __syncthreads();
    }

    float inv = 1.0f / (norm + 1e-6f);
    long  orow = (long)qrow * D;
#pragma unroll
    for (int rg = 0; rg < 4; ++rg) {
        int d0 = 8 * rg + 4 * h;
        float4 w0, w1;
        w0.x = oa0[4 * rg + 0] * inv;
        w0.y = oa0[4 * rg + 1] * inv;
        w0.z = oa0[4 * rg + 2] * inv;
        w0.w = oa0[4 * rg + 3] * inv;
        w1.x = oa1[4 * rg + 0] * inv;
        w1.y = oa1[4 * rg + 1] * inv;
        w1.z = oa1[4 * rg + 2] * inv;
        w1.w = oa1[4 * rg + 3] * inv;
        *(float4*)(Ob + orow + d0)      = w0;
        *(float4*)(Ob + orow + 32 + d0) = w1;
    }
}

extern "C" void kernel_launch(void* const* d_in, const int* in_sizes, int n_in,
                              void* d_out, int out_size, void* d_ws, size_t ws_size,
                              hipStream_t stream)
{
    (void)in_sizes; (void)n_in; (void)out_size;
    const float* q = (const float*)d_in[0];
    const float* k = (const float*)d_in[1];
    const float* v = (const float*)d_in[2];
    float*       o = (float*)d_out;

    const size_t need = 2 * TEN * sizeof(unsigned short);  // 33,554,432 B

    if (ws_size >= need) {
        unsigned short* kf_g = (unsigned short*)d_ws;
        unsigned short* vt_g = kf_g + TEN;

        dim3 pgrid(NBLK, NBH);
        hipLaunchKernelGGL(prep16, pgrid, dim3(256), 0, stream, k, v, kf_g, vt_g);

        dim3 grid(SLEN / QTILE, NBH);
        hipLaunchKernelGGL(fa_fwd3, grid, dim3(256), 0, stream, q, kf_g, vt_g, o);
    } else {
        dim3 grid(SLEN / QTILE, NBH);
        hipLaunchKernelGGL(fa_fwd, grid, dim3(256), 0, stream, q, k, v, o);
    }
}

// Round 8
// 308.377 us; speedup vs baseline: 1.8645x; 1.1037x over previous
//
#include <hip/hip_runtime.h>
#include <cstdint>
#include <cstddef>

typedef float     f32x16 __attribute__((ext_vector_type(16)));
typedef _Float16  f16x8  __attribute__((ext_vector_type(8)));
typedef __bf16    bf16x8 __attribute__((ext_vector_type(8)));
typedef unsigned  u32x2  __attribute__((ext_vector_type(2)));
typedef unsigned  u32x4  __attribute__((ext_vector_type(4)));

static_assert(sizeof(f16x8) == 16, "f16x8 must be 16B");

#define DEV __device__ __forceinline__

// ---- f16 helpers ----
DEV unsigned short f2h_bits(float f) {              // RNE via HW cvt
    _Float16 h = (_Float16)f;
    return __builtin_bit_cast(unsigned short, h);
}
DEV unsigned pack2h(float a, float b) {
    return (unsigned)f2h_bits(a) | ((unsigned)f2h_bits(b) << 16);
}
DEV unsigned cvt_pkrtz(float a, float b) {          // 1-instr packed cvt (RTZ)
    unsigned r;
    asm("v_cvt_pkrtz_f16_f32 %0, %1, %2" : "=v"(r) : "v"(a), "v"(b));
    return r;
}
DEV float exp2_hw(float x) {                        // v_exp_f32 = 2^x
    float r;
    asm("v_exp_f32 %0, %1" : "=v"(r) : "v"(x));
    return r;
}

// ---- bf16 helpers (fallback kernel only) ----
DEV unsigned f2bf_bits(float f) {
    unsigned u = __builtin_bit_cast(unsigned, f);
    return ((u + 0x7fffu + ((u >> 16) & 1u)) >> 16) & 0xffffu;
}
DEV float bf2f(unsigned bits) {
    return __builtin_bit_cast(float, bits << 16);
}
DEV unsigned pack2(float a, float b) {
    return f2bf_bits(a) | (f2bf_bits(b) << 16);
}

typedef __attribute__((address_space(1))) const void gas_t;
typedef __attribute__((address_space(3))) void       las_t;
DEV void gload_lds16(const void* g, void* l) {
    __builtin_amdgcn_global_load_lds((gas_t*)g, (las_t*)l, 16, 0, 0);
}

constexpr int D     = 64;
constexpr int SLEN  = 4096;
constexpr int KBLK  = 128;   // semantic block size (must match reference BLOCK_SIZE)
constexpr int NBLK  = SLEN / KBLK;
constexpr int QTILE = 128;   // 4 waves * 32 q-rows
constexpr int VSTR  = 136;   // (fallback kernel only)
constexpr int NBH   = 32;    // B*H
constexpr size_t IMG = 8192;                 // elems per (bh,kb) image (16 KB)
constexpr size_t TEN = (size_t)NBH * NBLK * IMG;  // elems per tensor
constexpr float QSCALE = 0.125f * 1.4426950408889634f;  // 1/sqrt(D) * log2(e)

// ============================================================================
// Pre-pass (f16): K -> frag-linear image, V -> swizzled V^T image. Both
// transforms staged through LDS so global reads AND writes are coalesced.
// ============================================================================
__global__ __launch_bounds__(256, 2)
void prep16(const float* __restrict__ Kg, const float* __restrict__ Vg,
            unsigned short* __restrict__ kf_g, unsigned short* __restrict__ vt_g)
{
    __shared__ __align__(16) unsigned short kstage[IMG];
    __shared__ __align__(16) unsigned short vstage[IMG];

    const int tid = threadIdx.x;
    const int kb  = blockIdx.x;
    const int bh  = blockIdx.y;
    const long base = (long)bh * SLEN * D;
    const int  kv0  = kb * KBLK;
    const size_t img = (size_t)(bh * NBLK + kb) * IMG;

    // ---- K: coalesced float4 reads -> f16 -> frag-linear into LDS ----
#pragma unroll
    for (int i = 0; i < 8; ++i) {
        int idx = i * 256 + tid;              // [0,2048) float4s
        int row = idx >> 4;                   // kv row 0..127
        int dq  = idx & 15;                   // d-quad 0..15
        float4 x = *(const float4*)(Kg + base + (long)(kv0 + row) * D + dq * 4);
        u32x2 p;
        p.x = pack2h(x.x, x.y);
        p.y = pack2h(x.z, x.w);
        int chunk = (row >> 5) * 256 + (dq >> 2) * 64 + (((dq >> 1) & 1) * 32) + (row & 31);
        *(u32x2*)&kstage[chunk * 8 + (dq & 1) * 4] = p;
    }

    // ---- V: coalesced reads -> quad-transpose -> f16 swizzled V^T into LDS ----
    const int e  = tid & 3;
    const int e0 = e & 1, e1 = e >> 1;
    const int DQi = (tid >> 2) & 15;
    const int w   = tid >> 6;
#pragma unroll
    for (int i = 0; i < 8; ++i) {
        int KQ = (i * 4 + w) * 4;             // kv-quad base
        int DQ = DQi * 4;                     // d-quad base
        float4 x = *(const float4*)(Vg + base + (long)(kv0 + KQ + e) * D + DQ);
        float f0 = x.x, f1 = x.y, f2 = x.z, f3 = x.w;
        float sA0 = e0 ? f0 : f1, sA1 = e0 ? f2 : f3;
        float rA0 = __shfl_xor(sA0, 1, 64), rA1 = __shfl_xor(sA1, 1, 64);
        float A0 = e0 ? rA0 : f0, A1 = e0 ? f1 : rA0;
        float A2 = e0 ? rA1 : f2, A3 = e0 ? f3 : rA1;
        float sB0 = e1 ? A0 : A2, sB1 = e1 ? A1 : A3;
        float rB0 = __shfl_xor(sB0, 2, 64), rB1 = __shfl_xor(sB1, 2, 64);
        float B0 = e1 ? rB0 : A0, B1 = e1 ? rB1 : A1;
        float B2 = e1 ? A2 : rB0, B3 = e1 ? A3 : rB1;
        int d = DQ + e;                       // B_i = V[KQ+i][d] = V^T[d][KQ+i]
        u32x2 p;
        p.x = pack2h(B0, B1);
        p.y = pack2h(B2, B3);
        int off = d * 128 + (KQ ^ ((d & 7) << 3));   // swizzled elem offset
        *(u32x2*)&vstage[off] = p;
    }

    __syncthreads();

    // ---- coalesced copy-out of both images ----
#pragma unroll
    for (int i = 0; i < 4; ++i) {
        size_t t8 = (size_t)(i * 256 + tid) * 8;
        *(u32x4*)&kf_g[img + t8] = *(const u32x4*)&kstage[t8];
        *(u32x4*)&vt_g[img + t8] = *(const u32x4*)&vstage[t8];
    }
}

// ============================================================================
// Main kernel: f16 MFMA, exp2-domain softmax, 2-phase double-buffered DMA.
// ============================================================================
__global__ __launch_bounds__(256, 2)
void fa_fwd4(const float* __restrict__ Qg,
             const unsigned short* __restrict__ kf_g,
             const unsigned short* __restrict__ vt_g,
             float* __restrict__ Og)
{
    __shared__ __align__(16) unsigned short kf_l0[IMG];
    __shared__ __align__(16) unsigned short vt_l0[IMG];
    __shared__ __align__(16) unsigned short kf_l1[IMG];
    __shared__ __align__(16) unsigned short vt_l1[IMG];

    const int tid = threadIdx.x;
    const int l   = tid & 63;
    const int w   = tid >> 6;
    const int h   = l >> 5;
    const int ln  = l & 31;

    const int  bh   = blockIdx.y;
    const long base = (long)bh * SLEN * D;
    const float* Qb = Qg + base;
    float*       Ob = Og + base;
    const unsigned short* kf_b = kf_g + (size_t)bh * NBLK * IMG;
    const unsigned short* vt_b = vt_g + (size_t)bh * NBLK * IMG;

    // ---- Q fragments, scale (1/8)*log2e folded (exp2-domain scores) ----
    const int qrow = blockIdx.x * QTILE + w * 32 + ln;
    f16x8 qf[4];
#pragma unroll
    for (int c = 0; c < 4; ++c) {
        const float* qp = Qb + (long)qrow * D + c * 16 + h * 8;
        float4 x0 = *(const float4*)qp;
        float4 x1 = *(const float4*)(qp + 4);
        u32x4 H;
        H.x = pack2h(x0.x * QSCALE, x0.y * QSCALE);
        H.y = pack2h(x0.z * QSCALE, x0.w * QSCALE);
        H.z = pack2h(x1.x * QSCALE, x1.y * QSCALE);
        H.w = pack2h(x1.z * QSCALE, x1.w * QSCALE);
        qf[c] = __builtin_bit_cast(f16x8, H);
    }

    f32x16 oa0 = {};   // O^T tile (d = 0..31 rows, q = lane&31 col)
    f32x16 oa1 = {};   // O^T tile (d = 32..63)
    f32x16 st[4];

    float mrun = -INFINITY;   // running max (log2 domain)
    float norm = 0.0f;

    const int so = (w * 64) * 8;       // wave-uniform LDS elem offset base
    const int go = so + l * 8;         // per-lane global elem offset base

    // ---- prologue: stage tile 0 into buffer 0 ----
    {
        const unsigned short* kfs = kf_b;
        const unsigned short* vts = vt_b;
#pragma unroll
        for (int i = 0; i < 4; ++i) {
            gload_lds16(kfs + go + i * 2048, &kf_l0[so + i * 2048]);
            gload_lds16(vts + go + i * 2048, &vt_l0[so + i * 2048]);
        }
    }
    __syncthreads();

#define FA_ITER(CURK, CURV, NXTK, NXTV, KB)                                     \
    do {                                                                        \
        if ((KB) + 1 < NBLK) {                                                  \
            const unsigned short* kfs = kf_b + (size_t)((KB) + 1) * IMG;        \
            const unsigned short* vts = vt_b + (size_t)((KB) + 1) * IMG;        \
            _Pragma("unroll")                                                   \
            for (int i = 0; i < 4; ++i) {                                       \
                gload_lds16(kfs + go + i * 2048, &NXTK[so + i * 2048]);         \
                gload_lds16(vts + go + i * 2048, &NXTV[so + i * 2048]);         \
            }                                                                   \
        }                                                                       \
        _Pragma("unroll")                                                       \
        for (int ki = 0; ki < 4; ++ki) {                                        \
            f32x16 acc = {};                                                    \
            _Pragma("unroll")                                                   \
            for (int c = 0; c < 4; ++c) {                                       \
                int ch = (ki * 4 + c) * 64 + l;                                 \
                f16x8 a = *(const f16x8*)&CURK[ch * 8];                         \
                acc = __builtin_amdgcn_mfma_f32_32x32x16_f16(a, qf[c], acc, 0, 0, 0); \
            }                                                                   \
            st[ki] = acc;                                                       \
        }                                                                       \
        float bm = -INFINITY;                                                   \
        _Pragma("unroll")                                                       \
        for (int ki = 0; ki < 4; ++ki)                                          \
            _Pragma("unroll")                                                   \
            for (int r = 0; r < 16; ++r) bm = fmaxf(bm, st[ki][r]);             \
        bm = fmaxf(bm, __shfl_xor(bm, 32, 64));                                 \
        float newm = fmaxf(mrun, bm);                                           \
        float sc   = exp2_hw(mrun - newm);                                      \
        mrun = newm;                                                            \
        float psum = 0.0f;                                                      \
        _Pragma("unroll")                                                       \
        for (int ki = 0; ki < 4; ++ki) {                                        \
            _Pragma("unroll")                                                   \
            for (int r = 0; r < 16; ++r) {                                      \
                float p = exp2_hw(st[ki][r] - bm);                              \
                st[ki][r] = p;                                                  \
                psum += p;                                                      \
            }                                                                   \
        }                                                                       \
        psum += __shfl_xor(psum, 32, 64);                                       \
        norm = norm * sc + psum;                                                \
        if (__any(sc != 1.0f)) {                                                \
            _Pragma("unroll")                                                   \
            for (int r = 0; r < 16; ++r) { oa0[r] *= sc; oa1[r] *= sc; }        \
        }                                                                       \
        f16x8 pf[8];                                                            \
        _Pragma("unroll")                                                       \
        for (int c = 0; c < 8; ++c) {                                           \
            int ki = c >> 1, half = c & 1;                                      \
            int rb = half * 8;                                                  \
            unsigned A0 = cvt_pkrtz(st[ki][rb + 0], st[ki][rb + 1]);            \
            unsigned A1 = cvt_pkrtz(st[ki][rb + 2], st[ki][rb + 3]);            \
            unsigned B0 = cvt_pkrtz(st[ki][rb + 4], st[ki][rb + 5]);            \
            unsigned B1 = cvt_pkrtz(st[ki][rb + 6], st[ki][rb + 7]);            \
            unsigned s0 = h ? A0 : B0;                                          \
            unsigned s1 = h ? A1 : B1;                                          \
            unsigned r0 = (unsigned)__shfl_xor((int)s0, 32, 64);                \
            unsigned r1 = (unsigned)__shfl_xor((int)s1, 32, 64);                \
            u32x4 f;                                                            \
            f.x = h ? r0 : A0;                                                  \
            f.y = h ? r1 : A1;                                                  \
            f.z = h ? B0 : r0;                                                  \
            f.w = h ? B1 : r1;                                                  \
            pf[c] = __builtin_bit_cast(f16x8, f);                               \
        }                                                                       \
        _Pragma("unroll")                                                       \
        for (int c = 0; c < 8; ++c) {                                           \
            const int kvo = c * 16 + h * 8;                                     \
            const int sa  = ln * 128 + (kvo ^ ((ln & 7) << 3));                 \
            f16x8 va = *(const f16x8*)&CURV[sa];                                \
            f16x8 vb = *(const f16x8*)&CURV[sa + 4096];                         \
            oa0 = __builtin_amdgcn_mfma_f32_32x32x16_f16(va, pf[c], oa0, 0, 0, 0); \
            oa1 = __builtin_amdgcn_mfma_f32_32x32x16_f16(vb, pf[c], oa1, 0, 0, 0); \
        }                                                                       \
        __syncthreads();                                                        \
    } while (0)

#pragma unroll 1
    for (int kb = 0; kb < NBLK; kb += 2) {
        FA_ITER(kf_l0, vt_l0, kf_l1, vt_l1, kb);
        FA_ITER(kf_l1, vt_l1, kf_l0, vt_l0, kb + 1);
    }
#undef FA_ITER

    // ---- epilogue ----
    float inv = 1.0f / (norm + 1e-6f);
    long  orow = (long)qrow * D;
#pragma unroll
    for (int rg = 0; rg < 4; ++rg) {
        int d0 = 8 * rg + 4 * h;
        float4 w0, w1;
        w0.x = oa0[4 * rg + 0] * inv;
        w0.y = oa0[4 * rg + 1] * inv;
        w0.z = oa0[4 * rg + 2] * inv;
        w0.w = oa0[4 * rg + 3] * inv;
        w1.x = oa1[4 * rg + 0] * inv;
        w1.y = oa1[4 * rg + 1] * inv;
        w1.z = oa1[4 * rg + 2] * inv;
        w1.w = oa1[4 * rg + 3] * inv;
        *(float4*)(Ob + orow + d0)      = w0;
        *(float4*)(Ob + orow + 32 + d0) = w1;
    }
}

// ============================================================================
// Fallback kernel (round-4, verified): in-kernel bf16 staging, if ws too small.
// ============================================================================
__global__ __launch_bounds__(256, 2)
void fa_fwd(const float* __restrict__ Qg, const float* __restrict__ Kg,
            const float* __restrict__ Vg, float* __restrict__ Og)
{
    __shared__ __align__(16) unsigned short khi[KBLK * D];
    __shared__ __align__(16) unsigned short klo[KBLK * D];
    __shared__ __align__(16) unsigned short vt[D * VSTR];

    const int tid = threadIdx.x;
    const int l   = tid & 63;
    const int w   = tid >> 6;
    const int h   = l >> 5;
    const int ln  = l & 31;

    const int  bh   = blockIdx.y;
    const long base = (long)bh * SLEN * D;
    const float* Qb = Qg + base;
    const float* Kb = Kg + base;
    const float* Vb = Vg + base;
    float*       Ob = Og + base;

    const int qrow = blockIdx.x * QTILE + w * 32 + ln;
    bf16x8 qhi[4], qlo[4];
#pragma unroll
    for (int c = 0; c < 4; ++c) {
        const float* qp = Qb + (long)qrow * D + c * 16 + h * 8;
        float4 x0 = *(const float4*)qp;
        float4 x1 = *(const float4*)(qp + 4);
        float xs[8] = {x0.x, x0.y, x0.z, x0.w, x1.x, x1.y, x1.z, x1.w};
        unsigned hw[4], lw[4];
#pragma unroll
        for (int j = 0; j < 4; ++j) {
            float a = xs[2 * j] * 0.125f, b = xs[2 * j + 1] * 0.125f;
            unsigned ha = f2bf_bits(a), hb = f2bf_bits(b);
            lw[j] = f2bf_bits(a - bf2f(ha)) | (f2bf_bits(b - bf2f(hb)) << 16);
            hw[j] = ha | (hb << 16);
        }
        u32x4 H = {hw[0], hw[1], hw[2], hw[3]};
        u32x4 L = {lw[0], lw[1], lw[2], lw[3]};
        qhi[c] = __builtin_bit_cast(bf16x8, H);
        qlo[c] = __builtin_bit_cast(bf16x8, L);
    }

    f32x16 oa0 = {};
    f32x16 oa1 = {};
    f32x16 st[4];

    float mrun = -INFINITY;
    float norm = 0.0f;

    const int e  = tid & 3;
    const int e0 = e & 1, e1 = e >> 1;
    const int DQi = (tid >> 2) & 15;

#pragma unroll 1
    for (int kb = 0; kb < NBLK; ++kb) {
        const int kv0 = kb * KBLK;

#pragma unroll
        for (int i = 0; i < 4; ++i) {
            int chunk = i * 256 + tid;
            int ki  = chunk >> 8;
            int c   = (chunk >> 6) & 3;
            int cl  = chunk & 63;
            int row = ki * 32 + (cl & 31);
            int d0  = c * 16 + (cl >> 5) * 8;
            const float* kp = Kb + (long)(kv0 + row) * D + d0;
            float4 x0 = *(const float4*)kp;
            float4 x1 = *(const float4*)(kp + 4);
            float xs[8] = {x0.x, x0.y, x0.z, x0.w, x1.x, x1.y, x1.z, x1.w};
            unsigned hw[4], lw[4];
#pragma unroll
            for (int j = 0; j < 4; ++j) {
                float a = xs[2 * j], b = xs[2 * j + 1];
                unsigned ha = f2bf_bits(a), hb = f2bf_bits(b);
                lw[j] = f2bf_bits(a - bf2f(ha)) | (f2bf_bits(b - bf2f(hb)) << 16);
                hw[j] = ha | (hb << 16);
            }
            u32x4 H = {hw[0], hw[1], hw[2], hw[3]};
            u32x4 L = {lw[0], lw[1], lw[2], lw[3]};
            *(u32x4*)&khi[chunk * 8] = H;
            *(u32x4*)&klo[chunk * 8] = L;
        }

#pragma unroll
        for (int i = 0; i < 8; ++i) {
            int KQ = (i * 4 + w) * 4;
            int DQ = DQi * 4;
            float4 x = *(const float4*)(Vb + (long)(kv0 + KQ + e) * D + DQ);
            float f0 = x.x, f1 = x.y, f2 = x.z, f3 = x.w;
            float sA0 = e0 ? f0 : f1, sA1 = e0 ? f2 : f3;
            float rA0 = __shfl_xor(sA0, 1, 64), rA1 = __shfl_xor(sA1, 1, 64);
            float A0 = e0 ? rA0 : f0, A1 = e0 ? f1 : rA0;
            float A2 = e0 ? rA1 : f2, A3 = e0 ? f3 : rA1;
            float sB0 = e1 ? A0 : A2, sB1 = e1 ? A1 : A3;
            float rB0 = __shfl_xor(sB0, 2, 64), rB1 = __shfl_xor(sB1, 2, 64);
            float B0 = e1 ? rB0 : A0, B1 = e1 ? rB1 : A1;
            float B2 = e1 ? A2 : rB0, B3 = e1 ? A3 : rB1;
            u32x2 p;
            p.x = pack2(B0, B1);
            p.y = pack2(B2, B3);
            *(u32x2*)&vt[(DQ + e) * VSTR + KQ] = p;
        }

        __syncthreads();

#pragma unroll
        for (int ki = 0; ki < 4; ++ki) {
            f32x16 acc = {};
#pragma unroll
            for (int c = 0; c < 4; ++c) {
                int ch = (ki * 4 + c) * 64 + l;
                bf16x8 ah = *(const bf16x8*)&khi[ch * 8];
                bf16x8 al = *(const bf16x8*)&klo[ch * 8];
                acc = __builtin_amdgcn_mfma_f32_32x32x16_bf16(ah, qhi[c], acc, 0, 0, 0);
                acc = __builtin_amdgcn_mfma_f32_32x32x16_bf16(ah, qlo[c], acc, 0, 0, 0);
                acc = __builtin_amdgcn_mfma_f32_32x32x16_bf16(al, qhi[c], acc, 0, 0, 0);
            }
            st[ki] = acc;
        }

        float bm = -INFINITY;
#pragma unroll
        for (int ki = 0; ki < 4; ++ki)
#pragma unroll
            for (int r = 0; r < 16; ++r) bm = fmaxf(bm, st[ki][r]);
        bm = fmaxf(bm, __shfl_xor(bm, 32, 64));

        float newm = fmaxf(mrun, bm);
        float sc   = __expf(mrun - newm);
        mrun = newm;

        float psum = 0.0f;
#pragma unroll
        for (int ki = 0; ki < 4; ++ki) {
#pragma unroll
            for (int r = 0; r < 16; ++r) {
                float p = __expf(st[ki][r] - bm);
                st[ki][r] = p;
                psum += p;
            }
        }
        psum += __shfl_xor(psum, 32, 64);
        norm = norm * sc + psum;

#pragma unroll
        for (int r = 0; r < 16; ++r) { oa0[r] *= sc; oa1[r] *= sc; }

        bf16x8 pf[8];
#pragma unroll
        for (int c = 0; c < 8; ++c) {
            int ki = c >> 1, half = c & 1;
            int rb = half * 8;
            unsigned A0 = pack2(st[ki][rb + 0], st[ki][rb + 1]);
            unsigned A1 = pack2(st[ki][rb + 2], st[ki][rb + 3]);
            unsigned B0 = pack2(st[ki][rb + 4], st[ki][rb + 5]);
            unsigned B1 = pack2(st[ki][rb + 6], st[ki][rb + 7]);
            unsigned s0 = h ? A0 : B0;
            unsigned s1 = h ? A1 : B1;
            unsigned r0 = (unsigned)__shfl_xor((int)s0, 32, 64);
            unsigned r1 = (unsigned)__shfl_xor((int)s1, 32, 64);
            u32x4 f;
            f.x = h ? r0 : A0;
            f.y = h ? r1 : A1;
            f.z = h ? B0 : r0;
            f.w = h ? B1 : r1;
            pf[c] = __builtin_bit_cast(bf16x8, f);
        }

#pragma unroll
        for (int c = 0; c < 8; ++c) {
            const int kvo = c * 16 + h * 8;
            bf16x8 va = *(const bf16x8*)&vt[(ln)      * VSTR + kvo];
            bf16x8 vb = *(const bf16x8*)&vt[(32 + ln) * VSTR + kvo];
            oa0 = __builtin_amdgcn_mfma_f32_32x32x16_bf16(va, pf[c], oa0, 0, 0, 0);
            oa1 = __builtin_amdgcn_mfma_f32_32x32x16_bf16(vb, pf[c], oa1, 0, 0, 0);
        }

        __syncthreads();
    }

    float inv = 1.0f / (norm + 1e-6f);
    long  orow = (long)qrow * D;
#pragma unroll
    for (int rg = 0; rg < 4; ++rg) {
        int d0 = 8 * rg + 4 * h;
        float4 w0, w1;
        w0.x = oa0[4 * rg + 0] * inv;
        w0.y = oa0[4 * rg + 1] * inv;
        w0.z = oa0[4 * rg + 2] * inv;
        w0.w = oa0[4 * rg + 3] * inv;
        w1.x = oa1[4 * rg + 0] * inv;
        w1.y = oa1[4 * rg + 1] * inv;
        w1.z = oa1[4 * rg + 2] * inv;
        w1.w = oa1[4 * rg + 3] * inv;
        *(float4*)(Ob + orow + d0)      = w0;
        *(float4*)(Ob + orow + 32 + d0) = w1;
    }
}

extern "C" void kernel_launch(void* const* d_in, const int* in_sizes, int n_in,
                              void* d_out, int out_size, void* d_ws, size_t ws_size,
                              hipStream_t stream)
{
    (void)in_sizes; (void)n_in; (void)out_size;
    const float* q = (const float*)d_in[0];
    const float* k = (const float*)d_in[1];
    const float* v = (const float*)d_in[2];
    float*       o = (float*)d_out;

    const size_t need = 2 * TEN * sizeof(unsigned short);  // 33,554,432 B

    if (ws_size >= need) {
        unsigned short* kf_g = (unsigned short*)d_ws;
        unsigned short* vt_g = kf_g + TEN;

        dim3 pgrid(NBLK, NBH);
        hipLaunchKernelGGL(prep16, pgrid, dim3(256), 0, stream, k, v, kf_g, vt_g);

        dim3 grid(SLEN / QTILE, NBH);
        hipLaunchKernelGGL(fa_fwd4, grid, dim3(256), 0, stream, q, kf_g, vt_g, o);
    } else {
        dim3 grid(SLEN / QTILE, NBH);
        hipLaunchKernelGGL(fa_fwd, grid, dim3(256), 0, stream, q, k, v, o);
    }
}